// Round 10
// baseline (150.348 us; speedup 1.0000x reference)
//
#include <hip/hip_runtime.h>

#define NLVL 16

// Per-level constants from the reference's _level_params() (f64 math -> f32).
constexpr float SCALEC[NLVL] = {
    15.0f, 19.15873679831797f, 24.39841683149119f, 31.0f,
    39.31747359663594f, 49.79683366298238f, 63.0f, 79.63494719327189f,
    100.59366732596477f, 127.0f, 160.26989438654376f, 202.18733465192954f,
    255.0f, 321.5397887730875f, 405.3746693038591f, 511.0f
};
constexpr int RESC[NLVL] = {
    16, 21, 26, 32, 41, 51, 64, 81, 102, 128, 162, 204, 256, 323, 407, 512
};
constexpr int OFFC[NLVL] = {
    0, 4096, 13360, 30936, 63704, 132632, 265288, 527432,
    1051720, 1576008, 2100296, 2624584, 3148872, 3673160, 4197448, 4721736
};
// Levels 0..6: lin (incl. corner offsets) < res^3 <= hsize -> mask is a no-op.
// Levels 7..15: hsize == 2^19 -> lin & 0x7FFFF; x-pair (e0,e0+1) wraps when
// e0 == 0x7FFFF -> cndmask fix with the level's entry 0 (uniform s_load).
constexpr int HMASK = 0x7FFFF;

#define NBUCKET 32768   // 5 bits/axis Morton over the occupied octant

// ---------------------------------------------------------------- gather core
template<int L>
__device__ __forceinline__ void lvl_issue(float x, float y, float z,
                                          const float* __restrict__ emb,
                                          float4& q0, float4& q1,
                                          float4& q2, float4& q3)
{
    constexpr float s  = SCALEC[L];
    constexpr int   r  = RESC[L];
    constexpr int   r2 = RESC[L] * RESC[L];
    constexpr int   off = OFFC[L];
    const float px = x * s, py = y * s, pz = z * s;
    const int lin = (int)floorf(px) + r * (int)floorf(py) + r2 * (int)floorf(pz);
    int i0 = lin, i1 = lin + r, i2 = lin + r2, i3 = lin + r2 + r;
    if constexpr (L >= 7) { i0 &= HMASK; i1 &= HMASK; i2 &= HMASK; i3 &= HMASK; }
    __builtin_memcpy(&q0, emb + 2 * (off + i0), 16);
    __builtin_memcpy(&q1, emb + 2 * (off + i1), 16);
    __builtin_memcpy(&q2, emb + 2 * (off + i2), 16);
    __builtin_memcpy(&q3, emb + 2 * (off + i3), 16);
}

template<int L>
__device__ __forceinline__ void lvl_finish(float x, float y, float z,
                                           const float* __restrict__ emb,
                                           float4 q0, float4 q1,
                                           float4 q2, float4 q3,
                                           float& a0, float& a1)
{
    constexpr float s  = SCALEC[L];
    constexpr int   r  = RESC[L];
    constexpr int   r2 = RESC[L] * RESC[L];
    constexpr int   off = OFFC[L];

    const float px = x * s, py = y * s, pz = z * s;
    const float tx = px - floorf(px), ty = py - floorf(py), tz = pz - floorf(pz);

    if constexpr (L >= 7) {
        const int lin = (int)floorf(px) + r * (int)floorf(py) + r2 * (int)floorf(pz);
        const int i0 = lin & HMASK, i1 = (lin + r) & HMASK;
        const int i2 = (lin + r2) & HMASK, i3 = (lin + r2 + r) & HMASK;
        const float f0x = emb[2 * off], f0y = emb[2 * off + 1];  // uniform s_load
        q0.z = (i0 == HMASK) ? f0x : q0.z;  q0.w = (i0 == HMASK) ? f0y : q0.w;
        q1.z = (i1 == HMASK) ? f0x : q1.z;  q1.w = (i1 == HMASK) ? f0y : q1.w;
        q2.z = (i2 == HMASK) ? f0x : q2.z;  q2.w = (i2 == HMASK) ? f0y : q2.w;
        q3.z = (i3 == HMASK) ? f0x : q3.z;  q3.w = (i3 == HMASK) ? f0y : q3.w;
    }

    const float wx1 = tx, wx0 = 1.0f - tx;
    const float wy1 = ty, wy0 = 1.0f - ty;
    const float wz1 = tz, wz0 = 1.0f - tz;
    const float w00 = wy0 * wz0, w10 = wy1 * wz0;
    const float w01 = wy0 * wz1, w11 = wy1 * wz1;
    float r0 = 0.0f, r1 = 0.0f;
    r0 = fmaf(w00 * wx0, q0.x, r0); r1 = fmaf(w00 * wx0, q0.y, r1);
    r0 = fmaf(w00 * wx1, q0.z, r0); r1 = fmaf(w00 * wx1, q0.w, r1);
    r0 = fmaf(w10 * wx0, q1.x, r0); r1 = fmaf(w10 * wx0, q1.y, r1);
    r0 = fmaf(w10 * wx1, q1.z, r0); r1 = fmaf(w10 * wx1, q1.w, r1);
    r0 = fmaf(w01 * wx0, q2.x, r0); r1 = fmaf(w01 * wx0, q2.y, r1);
    r0 = fmaf(w01 * wx1, q2.z, r0); r1 = fmaf(w01 * wx1, q2.w, r1);
    r0 = fmaf(w11 * wx0, q3.x, r0); r1 = fmaf(w11 * wx0, q3.y, r1);
    r0 = fmaf(w11 * wx1, q3.z, r0); r1 = fmaf(w11 * wx1, q3.w, r1);
    a0 = r0; a1 = r1;
}

// Pair {G, G+8} for one point -> packed float4 of 4 encoder channels.
template<int G>
__device__ __forceinline__ float4 enc_point(float x, float y, float z,
                                            const float* __restrict__ emb)
{
    float4 a0, a1, a2, a3, b0, b1, b2, b3;
    lvl_issue<G>(x, y, z, emb, a0, a1, a2, a3);
    lvl_issue<G + 8>(x, y, z, emb, b0, b1, b2, b3);
    float e0, e1, e2, e3;
    lvl_finish<G>(x, y, z, emb, a0, a1, a2, a3, e0, e1);
    lvl_finish<G + 8>(x, y, z, emb, b0, b1, b2, b3, e2, e3);
    return make_float4(e0, e1, e2, e3);
}

// ---------------------------------------------------------------- sort passes
__device__ __forceinline__ int bucket_key(float x, float y, float z)
{
    // x,y,z in [0.5,1) (inputs are (c+1)/2, c in [0,1)); clamp for safety.
    int kx = (int)((x * 2.0f - 1.0f) * 32.0f);
    int ky = (int)((y * 2.0f - 1.0f) * 32.0f);
    int kz = (int)((z * 2.0f - 1.0f) * 32.0f);
    kx = min(31, max(0, kx)); ky = min(31, max(0, ky)); kz = min(31, max(0, kz));
    int m = 0;
#pragma unroll
    for (int b = 0; b < 5; ++b) {
        m |= (((kx >> b) & 1) << (3 * b))
           | (((ky >> b) & 1) << (3 * b + 1))
           | (((kz >> b) & 1) << (3 * b + 2));
    }
    return m;
}

__global__ __launch_bounds__(256)
void zero_kernel(int* __restrict__ counts)
{
    const int i = blockIdx.x * 256 + threadIdx.x;
    if (i < NBUCKET) counts[i] = 0;
}

__global__ __launch_bounds__(256)
void hist_kernel(const float* __restrict__ coords, int* __restrict__ counts, int n)
{
    const int p = blockIdx.x * 256 + threadIdx.x;
    if (p >= n) return;
    const float x = (coords[p * 3 + 0] + 1.0f) * 0.5f;
    const float y = (coords[p * 3 + 1] + 1.0f) * 0.5f;
    const float z = (coords[p * 3 + 2] + 1.0f) * 0.5f;
    atomicAdd(&counts[bucket_key(x, y, z)], 1);
}

__global__ __launch_bounds__(1024)
void scan_kernel(const int* __restrict__ counts, int* __restrict__ offsets)
{
    __shared__ int part[1024];
    const int t = threadIdx.x;
    const int base = t * (NBUCKET / 1024);   // 32 each
    int sum = 0;
#pragma unroll
    for (int i = 0; i < NBUCKET / 1024; ++i) sum += counts[base + i];
    part[t] = sum;
    __syncthreads();
    // Hillis-Steele inclusive scan over 1024 partials.
    for (int s = 1; s < 1024; s <<= 1) {
        const int v = (t >= s) ? part[t - s] : 0;
        __syncthreads();
        part[t] += v;
        __syncthreads();
    }
    int run = part[t] - sum;   // exclusive prefix of this thread's chunk
#pragma unroll
    for (int i = 0; i < NBUCKET / 1024; ++i) {
        offsets[base + i] = run;
        run += counts[base + i];
    }
}

__global__ __launch_bounds__(256)
void scatter_kernel(const float* __restrict__ coords, int* __restrict__ offsets,
                    float4* __restrict__ sc, int n)
{
    const int p = blockIdx.x * 256 + threadIdx.x;
    if (p >= n) return;
    const float x = (coords[p * 3 + 0] + 1.0f) * 0.5f;
    const float y = (coords[p * 3 + 1] + 1.0f) * 0.5f;
    const float z = (coords[p * 3 + 2] + 1.0f) * 0.5f;
    const int dst = atomicAdd(&offsets[bucket_key(x, y, z)], 1);
    sc[dst] = make_float4(x, y, z, __int_as_float(p));
}

// ---------------------------------------------------------------- pass 1: enc
// pair = blockIdx.x & 7: XCD-affine level-pair (r8: FETCH 103 -> 43 MB).
// Sorted input: a wave's 64 lanes are spatial neighbors -> corner loads
// share cache lines -> far fewer unique-line misses per wave.
__global__ __launch_bounds__(256)
void enc_sorted(const float4* __restrict__ sc, const float* __restrict__ emb,
                float4* __restrict__ encws, int n)
{
    const int pair = blockIdx.x & 7;
    const int q = (blockIdx.x >> 3) * 256 + threadIdx.x;
    if (q >= n) return;
    const float4 c = sc[q];
    switch (pair) {
        case 0: encws[(size_t)0 * n + q] = enc_point<0>(c.x, c.y, c.z, emb); break;
        case 1: encws[(size_t)1 * n + q] = enc_point<1>(c.x, c.y, c.z, emb); break;
        case 2: encws[(size_t)2 * n + q] = enc_point<2>(c.x, c.y, c.z, emb); break;
        case 3: encws[(size_t)3 * n + q] = enc_point<3>(c.x, c.y, c.z, emb); break;
        case 4: encws[(size_t)4 * n + q] = enc_point<4>(c.x, c.y, c.z, emb); break;
        case 5: encws[(size_t)5 * n + q] = enc_point<5>(c.x, c.y, c.z, emb); break;
        case 6: encws[(size_t)6 * n + q] = enc_point<6>(c.x, c.y, c.z, emb); break;
        default: encws[(size_t)7 * n + q] = enc_point<7>(c.x, c.y, c.z, emb); break;
    }
}

__global__ __launch_bounds__(256)
void enc_unsorted(const float* __restrict__ coords, const float* __restrict__ emb,
                  float4* __restrict__ encws, int n)
{
    const int pair = blockIdx.x & 7;
    const int q = (blockIdx.x >> 3) * 256 + threadIdx.x;
    if (q >= n) return;
    const float x = (coords[q * 3 + 0] + 1.0f) * 0.5f;
    const float y = (coords[q * 3 + 1] + 1.0f) * 0.5f;
    const float z = (coords[q * 3 + 2] + 1.0f) * 0.5f;
    switch (pair) {
        case 0: encws[(size_t)0 * n + q] = enc_point<0>(x, y, z, emb); break;
        case 1: encws[(size_t)1 * n + q] = enc_point<1>(x, y, z, emb); break;
        case 2: encws[(size_t)2 * n + q] = enc_point<2>(x, y, z, emb); break;
        case 3: encws[(size_t)3 * n + q] = enc_point<3>(x, y, z, emb); break;
        case 4: encws[(size_t)4 * n + q] = enc_point<4>(x, y, z, emb); break;
        case 5: encws[(size_t)5 * n + q] = enc_point<5>(x, y, z, emb); break;
        case 6: encws[(size_t)6 * n + q] = enc_point<6>(x, y, z, emb); break;
        default: encws[(size_t)7 * n + q] = enc_point<7>(x, y, z, emb); break;
    }
}

// ---------------------------------------------------------------- pass 2: MLP
__global__ __launch_bounds__(256)
void mlp_kernel(const float4* __restrict__ encws, const float4* __restrict__ sc,
                const float* __restrict__ W0, const float* __restrict__ b0,
                const float* __restrict__ W1, const float* __restrict__ b1,
                const float* __restrict__ W2, const float* __restrict__ b2,
                float* __restrict__ out, int n)
{
    const int p = blockIdx.x * 256 + threadIdx.x;
    if (p >= n) return;

    float enc[32];
#pragma unroll
    for (int g = 0; g < 8; ++g) {                       // 8 coalesced 16B loads
        const float4 v = encws[(size_t)g * n + p];
        enc[2 * g + 0]       = v.x;
        enc[2 * g + 1]       = v.y;
        enc[2 * (g + 8) + 0] = v.z;
        enc[2 * (g + 8) + 1] = v.w;
    }

    float h0[32];
#pragma unroll
    for (int j = 0; j < 32; ++j) h0[j] = b0[j];
#pragma unroll
    for (int i = 0; i < 32; ++i) {
        const float e = enc[i];
#pragma unroll
        for (int j = 0; j < 32; ++j) h0[j] = fmaf(e, W0[i * 32 + j], h0[j]);
    }
#pragma unroll
    for (int j = 0; j < 32; ++j) h0[j] = (h0[j] >= 0.0f) ? h0[j] : 0.01f * h0[j];

    float h1[32];
#pragma unroll
    for (int j = 0; j < 32; ++j) h1[j] = b1[j];
#pragma unroll
    for (int i = 0; i < 32; ++i) {
        const float e = h0[i];
#pragma unroll
        for (int j = 0; j < 32; ++j) h1[j] = fmaf(e, W1[i * 32 + j], h1[j]);
    }
#pragma unroll
    for (int j = 0; j < 32; ++j) h1[j] = (h1[j] >= 0.0f) ? h1[j] : 0.01f * h1[j];

    float acc = b2[0];
#pragma unroll
    for (int j = 0; j < 32; ++j) acc = fmaf(h1[j], W2[j], acc);

    const int o = sc ? __float_as_int(sc[p].w) : p;   // unsort on final store
    out[o] = acc;
}

// ---------------- Fallback: fused single kernel (r3 structure) ---------------
template<int L>
__device__ __forceinline__ void fuse_level(float x, float y, float z,
                                           const float* __restrict__ emb,
                                           float4 q0, float4 q1,
                                           float4 q2, float4 q3,
                                           float* __restrict__ h0,
                                           const float* __restrict__ W0)
{
    float a0, a1;
    lvl_finish<L>(x, y, z, emb, q0, q1, q2, q3, a0, a1);
#pragma unroll
    for (int j = 0; j < 32; ++j)
        h0[j] = fmaf(a0, W0[(2 * L + 0) * 32 + j], h0[j]);
#pragma unroll
    for (int j = 0; j < 32; ++j)
        h0[j] = fmaf(a1, W0[(2 * L + 1) * 32 + j], h0[j]);
}

__global__ __launch_bounds__(256, 4)
void fused_kernel(const float* __restrict__ coords,
                  const float* __restrict__ emb,
                  const float* __restrict__ W0, const float* __restrict__ b0,
                  const float* __restrict__ W1, const float* __restrict__ b1,
                  const float* __restrict__ W2, const float* __restrict__ b2,
                  float* __restrict__ out, int n)
{
    const int tid = blockIdx.x * blockDim.x + threadIdx.x;
    if (tid >= n) return;
    const float x = (coords[tid * 3 + 0] + 1.0f) * 0.5f;
    const float y = (coords[tid * 3 + 1] + 1.0f) * 0.5f;
    const float z = (coords[tid * 3 + 2] + 1.0f) * 0.5f;

    float h0[32];
#pragma unroll
    for (int j = 0; j < 32; ++j) h0[j] = b0[j];

    float4 a0, a1, a2, a3, b0r, b1r, b2r, b3r;
#define ISS_A(L) lvl_issue<L>(x, y, z, emb, a0, a1, a2, a3);
#define ISS_B(L) lvl_issue<L>(x, y, z, emb, b0r, b1r, b2r, b3r);
#define FUS_A(L) fuse_level<L>(x, y, z, emb, a0, a1, a2, a3, h0, W0);
#define FUS_B(L) fuse_level<L>(x, y, z, emb, b0r, b1r, b2r, b3r, h0, W0);
    ISS_A(0)
    ISS_B(1)  FUS_A(0)
    ISS_A(2)  FUS_B(1)
    ISS_B(3)  FUS_A(2)
    ISS_A(4)  FUS_B(3)
    ISS_B(5)  FUS_A(4)
    ISS_A(6)  FUS_B(5)
    ISS_B(7)  FUS_A(6)
    ISS_A(8)  FUS_B(7)
    ISS_B(9)  FUS_A(8)
    ISS_A(10) FUS_B(9)
    ISS_B(11) FUS_A(10)
    ISS_A(12) FUS_B(11)
    ISS_B(13) FUS_A(12)
    ISS_A(14) FUS_B(13)
    ISS_B(15) FUS_A(14)
    FUS_B(15)
#undef ISS_A
#undef ISS_B
#undef FUS_A
#undef FUS_B

#pragma unroll
    for (int j = 0; j < 32; ++j) h0[j] = (h0[j] >= 0.0f) ? h0[j] : 0.01f * h0[j];
    float h1[32];
#pragma unroll
    for (int j = 0; j < 32; ++j) h1[j] = b1[j];
#pragma unroll
    for (int i = 0; i < 32; ++i) {
        const float e = h0[i];
#pragma unroll
        for (int j = 0; j < 32; ++j) h1[j] = fmaf(e, W1[i * 32 + j], h1[j]);
    }
#pragma unroll
    for (int j = 0; j < 32; ++j) h1[j] = (h1[j] >= 0.0f) ? h1[j] : 0.01f * h1[j];
    float acc = b2[0];
#pragma unroll
    for (int j = 0; j < 32; ++j) acc = fmaf(h1[j], W2[j], acc);
    out[tid] = acc;
}

extern "C" void kernel_launch(void* const* d_in, const int* in_sizes, int n_in,
                              void* d_out, int out_size, void* d_ws, size_t ws_size,
                              hipStream_t stream) {
    const float* coords = (const float*)d_in[0];   // [N,1,3]
    const float* emb    = (const float*)d_in[1];   // [total,1,2]
    const float* W0     = (const float*)d_in[2];
    const float* b0     = (const float*)d_in[3];
    const float* W1     = (const float*)d_in[4];
    const float* b1     = (const float*)d_in[5];
    const float* W2     = (const float*)d_in[6];
    const float* b2     = (const float*)d_in[7];
    float* out = (float*)d_out;

    const int n = in_sizes[0] / 3;   // 262144
    const int nb = (n + 255) / 256;

    // ws layout: counts[32K] | offsets[32K] | sc float4[n] | enc float4[8n]
    char* base = (char*)d_ws;
    int*    counts  = (int*)base;
    int*    offsets = (int*)(base + NBUCKET * 4);
    float4* sc      = (float4*)(base + 2 * (size_t)NBUCKET * 4);
    float4* encws   = (float4*)(base + 2 * (size_t)NBUCKET * 4 + (size_t)n * 16);

    const size_t need_sorted = 2 * (size_t)NBUCKET * 4 + (size_t)n * 16
                             + (size_t)n * 128;                 // ~38.0 MB
    const size_t need_plain  = (size_t)n * 128;                 // 33.6 MB

    if (ws_size >= need_sorted) {
        zero_kernel<<<(NBUCKET + 255) / 256, 256, 0, stream>>>(counts);
        hist_kernel<<<nb, 256, 0, stream>>>(coords, counts, n);
        scan_kernel<<<1, 1024, 0, stream>>>(counts, offsets);
        scatter_kernel<<<nb, 256, 0, stream>>>(coords, offsets, sc, n);
        enc_sorted<<<nb * 8, 256, 0, stream>>>(sc, emb, encws, n);
        mlp_kernel<<<nb, 256, 0, stream>>>(encws, sc,
                                           W0, b0, W1, b1, W2, b2, out, n);
    } else if (ws_size >= need_plain) {
        float4* encp = (float4*)d_ws;
        enc_unsorted<<<nb * 8, 256, 0, stream>>>(coords, emb, encp, n);
        mlp_kernel<<<nb, 256, 0, stream>>>(encp, nullptr,
                                           W0, b0, W1, b1, W2, b2, out, n);
    } else {
        fused_kernel<<<nb, 256, 0, stream>>>(coords, emb,
                                             W0, b0, W1, b1, W2, b2, out, n);
    }
}

// Round 11
// 149.589 us; speedup vs baseline: 1.0051x; 1.0051x over previous
//
#include <hip/hip_runtime.h>

#define NLVL 16

// Per-level constants from the reference's _level_params() (f64 math -> f32).
constexpr float SCALEC[NLVL] = {
    15.0f, 19.15873679831797f, 24.39841683149119f, 31.0f,
    39.31747359663594f, 49.79683366298238f, 63.0f, 79.63494719327189f,
    100.59366732596477f, 127.0f, 160.26989438654376f, 202.18733465192954f,
    255.0f, 321.5397887730875f, 405.3746693038591f, 511.0f
};
constexpr int RESC[NLVL] = {
    16, 21, 26, 32, 41, 51, 64, 81, 102, 128, 162, 204, 256, 323, 407, 512
};
constexpr int OFFC[NLVL] = {
    0, 4096, 13360, 30936, 63704, 132632, 265288, 527432,
    1051720, 1576008, 2100296, 2624584, 3148872, 3673160, 4197448, 4721736
};
// Levels 0..6: lin (incl. corner offsets) < res^3 <= hsize -> mask is a no-op.
// Levels 7..15: hsize == 2^19 -> lin & 0x7FFFF; x-pair (e0,e0+1) wraps when
// e0 == 0x7FFFF -> cndmask fix with the level's entry 0 (uniform s_load).
constexpr int HMASK = 0x7FFFF;

#define NBUCKET 32768   // 5 bits/axis Morton over the occupied octant

// ---------------------------------------------------------------- gather core
template<int L>
__device__ __forceinline__ void lvl_issue(float x, float y, float z,
                                          const float* __restrict__ emb,
                                          float4& q0, float4& q1,
                                          float4& q2, float4& q3)
{
    constexpr float s  = SCALEC[L];
    constexpr int   r  = RESC[L];
    constexpr int   r2 = RESC[L] * RESC[L];
    constexpr int   off = OFFC[L];
    const float px = x * s, py = y * s, pz = z * s;
    const int lin = (int)floorf(px) + r * (int)floorf(py) + r2 * (int)floorf(pz);
    int i0 = lin, i1 = lin + r, i2 = lin + r2, i3 = lin + r2 + r;
    if constexpr (L >= 7) { i0 &= HMASK; i1 &= HMASK; i2 &= HMASK; i3 &= HMASK; }
    __builtin_memcpy(&q0, emb + 2 * (off + i0), 16);
    __builtin_memcpy(&q1, emb + 2 * (off + i1), 16);
    __builtin_memcpy(&q2, emb + 2 * (off + i2), 16);
    __builtin_memcpy(&q3, emb + 2 * (off + i3), 16);
}

template<int L>
__device__ __forceinline__ void lvl_finish(float x, float y, float z,
                                           const float* __restrict__ emb,
                                           float4 q0, float4 q1,
                                           float4 q2, float4 q3,
                                           float& a0, float& a1)
{
    constexpr float s  = SCALEC[L];
    constexpr int   r  = RESC[L];
    constexpr int   r2 = RESC[L] * RESC[L];
    constexpr int   off = OFFC[L];

    const float px = x * s, py = y * s, pz = z * s;
    const float tx = px - floorf(px), ty = py - floorf(py), tz = pz - floorf(pz);

    if constexpr (L >= 7) {
        const int lin = (int)floorf(px) + r * (int)floorf(py) + r2 * (int)floorf(pz);
        const int i0 = lin & HMASK, i1 = (lin + r) & HMASK;
        const int i2 = (lin + r2) & HMASK, i3 = (lin + r2 + r) & HMASK;
        const float f0x = emb[2 * off], f0y = emb[2 * off + 1];  // uniform s_load
        q0.z = (i0 == HMASK) ? f0x : q0.z;  q0.w = (i0 == HMASK) ? f0y : q0.w;
        q1.z = (i1 == HMASK) ? f0x : q1.z;  q1.w = (i1 == HMASK) ? f0y : q1.w;
        q2.z = (i2 == HMASK) ? f0x : q2.z;  q2.w = (i2 == HMASK) ? f0y : q2.w;
        q3.z = (i3 == HMASK) ? f0x : q3.z;  q3.w = (i3 == HMASK) ? f0y : q3.w;
    }

    const float wx1 = tx, wx0 = 1.0f - tx;
    const float wy1 = ty, wy0 = 1.0f - ty;
    const float wz1 = tz, wz0 = 1.0f - tz;
    const float w00 = wy0 * wz0, w10 = wy1 * wz0;
    const float w01 = wy0 * wz1, w11 = wy1 * wz1;
    float r0 = 0.0f, r1 = 0.0f;
    r0 = fmaf(w00 * wx0, q0.x, r0); r1 = fmaf(w00 * wx0, q0.y, r1);
    r0 = fmaf(w00 * wx1, q0.z, r0); r1 = fmaf(w00 * wx1, q0.w, r1);
    r0 = fmaf(w10 * wx0, q1.x, r0); r1 = fmaf(w10 * wx0, q1.y, r1);
    r0 = fmaf(w10 * wx1, q1.z, r0); r1 = fmaf(w10 * wx1, q1.w, r1);
    r0 = fmaf(w01 * wx0, q2.x, r0); r1 = fmaf(w01 * wx0, q2.y, r1);
    r0 = fmaf(w01 * wx1, q2.z, r0); r1 = fmaf(w01 * wx1, q2.w, r1);
    r0 = fmaf(w11 * wx0, q3.x, r0); r1 = fmaf(w11 * wx0, q3.y, r1);
    r0 = fmaf(w11 * wx1, q3.z, r0); r1 = fmaf(w11 * wx1, q3.w, r1);
    a0 = r0; a1 = r1;
}

// Pair {G, G+8} for one point -> packed float4 of 4 encoder channels.
template<int G>
__device__ __forceinline__ float4 enc_point(float x, float y, float z,
                                            const float* __restrict__ emb)
{
    float4 a0, a1, a2, a3, b0, b1, b2, b3;
    lvl_issue<G>(x, y, z, emb, a0, a1, a2, a3);
    lvl_issue<G + 8>(x, y, z, emb, b0, b1, b2, b3);
    float e0, e1, e2, e3;
    lvl_finish<G>(x, y, z, emb, a0, a1, a2, a3, e0, e1);
    lvl_finish<G + 8>(x, y, z, emb, b0, b1, b2, b3, e2, e3);
    return make_float4(e0, e1, e2, e3);
}

// ---------------------------------------------------------------- sort passes
__device__ __forceinline__ int bucket_key(float x, float y, float z)
{
    // x,y,z in [0.5,1) (inputs are (c+1)/2, c in [0,1)); clamp for safety.
    int kx = (int)((x * 2.0f - 1.0f) * 32.0f);
    int ky = (int)((y * 2.0f - 1.0f) * 32.0f);
    int kz = (int)((z * 2.0f - 1.0f) * 32.0f);
    kx = min(31, max(0, kx)); ky = min(31, max(0, ky)); kz = min(31, max(0, kz));
    int m = 0;
#pragma unroll
    for (int b = 0; b < 5; ++b) {
        m |= (((kx >> b) & 1) << (3 * b))
           | (((ky >> b) & 1) << (3 * b + 1))
           | (((kz >> b) & 1) << (3 * b + 2));
    }
    return m;
}

__global__ __launch_bounds__(256)
void hist_kernel(const float* __restrict__ coords, int* __restrict__ counts, int n)
{
    const int p = blockIdx.x * 256 + threadIdx.x;
    if (p >= n) return;
    const float x = (coords[p * 3 + 0] + 1.0f) * 0.5f;
    const float y = (coords[p * 3 + 1] + 1.0f) * 0.5f;
    const float z = (coords[p * 3 + 2] + 1.0f) * 0.5f;
    atomicAdd(&counts[bucket_key(x, y, z)], 1);
}

__global__ __launch_bounds__(1024)
void scan_kernel(const int* __restrict__ counts, int* __restrict__ offsets)
{
    __shared__ int part[1024];
    const int t = threadIdx.x;
    const int base = t * 32;                 // contiguous 32-bucket chunk
    int v[32];
    const int4* c4 = (const int4*)(counts + base);
#pragma unroll
    for (int i = 0; i < 8; ++i) {
        const int4 q = c4[i];
        v[4 * i] = q.x; v[4 * i + 1] = q.y; v[4 * i + 2] = q.z; v[4 * i + 3] = q.w;
    }
    int sum = 0;
#pragma unroll
    for (int i = 0; i < 32; ++i) sum += v[i];
    part[t] = sum;
    __syncthreads();
    for (int s = 1; s < 1024; s <<= 1) {     // Hillis-Steele inclusive scan
        const int pv = (t >= s) ? part[t - s] : 0;
        __syncthreads();
        part[t] += pv;
        __syncthreads();
    }
    int run = part[t] - sum;                 // exclusive prefix of this chunk
    int o[32];
#pragma unroll
    for (int i = 0; i < 32; ++i) { o[i] = run; run += v[i]; }
    int4* o4 = (int4*)(offsets + base);
#pragma unroll
    for (int i = 0; i < 8; ++i)
        o4[i] = make_int4(o[4 * i], o[4 * i + 1], o[4 * i + 2], o[4 * i + 3]);
}

__global__ __launch_bounds__(256)
void scatter_kernel(const float* __restrict__ coords, int* __restrict__ offsets,
                    float4* __restrict__ sc, int n)
{
    const int p = blockIdx.x * 256 + threadIdx.x;
    if (p >= n) return;
    const float x = (coords[p * 3 + 0] + 1.0f) * 0.5f;
    const float y = (coords[p * 3 + 1] + 1.0f) * 0.5f;
    const float z = (coords[p * 3 + 2] + 1.0f) * 0.5f;
    const int dst = atomicAdd(&offsets[bucket_key(x, y, z)], 1);
    sc[dst] = make_float4(x, y, z, __int_as_float(p));
}

// ---------------------------------------------------------------- pass 1: enc
// pair = blockIdx.x & 7: XCD-affine level-pair (r8: FETCH 103 -> 43 MB).
// Sorted input: a wave's 64 lanes are spatial neighbors -> corner loads
// share cache lines (L1/L2 hits) -> far fewer unique-line misses per wave.
__global__ __launch_bounds__(256)
void enc_sorted(const float4* __restrict__ sc, const float* __restrict__ emb,
                float4* __restrict__ encws, int n)
{
    const int pair = blockIdx.x & 7;
    const int q = (blockIdx.x >> 3) * 256 + threadIdx.x;
    if (q >= n) return;
    const float4 c = sc[q];
    switch (pair) {
        case 0: encws[(size_t)0 * n + q] = enc_point<0>(c.x, c.y, c.z, emb); break;
        case 1: encws[(size_t)1 * n + q] = enc_point<1>(c.x, c.y, c.z, emb); break;
        case 2: encws[(size_t)2 * n + q] = enc_point<2>(c.x, c.y, c.z, emb); break;
        case 3: encws[(size_t)3 * n + q] = enc_point<3>(c.x, c.y, c.z, emb); break;
        case 4: encws[(size_t)4 * n + q] = enc_point<4>(c.x, c.y, c.z, emb); break;
        case 5: encws[(size_t)5 * n + q] = enc_point<5>(c.x, c.y, c.z, emb); break;
        case 6: encws[(size_t)6 * n + q] = enc_point<6>(c.x, c.y, c.z, emb); break;
        default: encws[(size_t)7 * n + q] = enc_point<7>(c.x, c.y, c.z, emb); break;
    }
}

__global__ __launch_bounds__(256)
void enc_unsorted(const float* __restrict__ coords, const float* __restrict__ emb,
                  float4* __restrict__ encws, int n)
{
    const int pair = blockIdx.x & 7;
    const int q = (blockIdx.x >> 3) * 256 + threadIdx.x;
    if (q >= n) return;
    const float x = (coords[q * 3 + 0] + 1.0f) * 0.5f;
    const float y = (coords[q * 3 + 1] + 1.0f) * 0.5f;
    const float z = (coords[q * 3 + 2] + 1.0f) * 0.5f;
    switch (pair) {
        case 0: encws[(size_t)0 * n + q] = enc_point<0>(x, y, z, emb); break;
        case 1: encws[(size_t)1 * n + q] = enc_point<1>(x, y, z, emb); break;
        case 2: encws[(size_t)2 * n + q] = enc_point<2>(x, y, z, emb); break;
        case 3: encws[(size_t)3 * n + q] = enc_point<3>(x, y, z, emb); break;
        case 4: encws[(size_t)4 * n + q] = enc_point<4>(x, y, z, emb); break;
        case 5: encws[(size_t)5 * n + q] = enc_point<5>(x, y, z, emb); break;
        case 6: encws[(size_t)6 * n + q] = enc_point<6>(x, y, z, emb); break;
        default: encws[(size_t)7 * n + q] = enc_point<7>(x, y, z, emb); break;
    }
}

// ---------------------------------------------------------------- pass 2: MLP
// Streaming layer-0: each float4 of encws is FMA'd into h0 immediately; the
// 32-wide enc vector is never materialized -> ~45 live VGPRs, no spill.
__global__ __launch_bounds__(256)
void mlp_kernel(const float4* __restrict__ encws, const float4* __restrict__ sc,
                const float* __restrict__ W0, const float* __restrict__ b0,
                const float* __restrict__ W1, const float* __restrict__ b1,
                const float* __restrict__ W2, const float* __restrict__ b2,
                float* __restrict__ out, int n)
{
    const int p = blockIdx.x * 256 + threadIdx.x;
    if (p >= n) return;

    float h0[32];
#pragma unroll
    for (int j = 0; j < 32; ++j) h0[j] = b0[j];

#pragma unroll
    for (int g = 0; g < 8; ++g) {
        const float4 v = encws[(size_t)g * n + p];       // coalesced 16B
        // channels: 2g, 2g+1 (level g), 16+2g, 17+2g (level g+8)
#pragma unroll
        for (int j = 0; j < 32; ++j) h0[j] = fmaf(v.x, W0[(2 * g + 0) * 32 + j], h0[j]);
#pragma unroll
        for (int j = 0; j < 32; ++j) h0[j] = fmaf(v.y, W0[(2 * g + 1) * 32 + j], h0[j]);
#pragma unroll
        for (int j = 0; j < 32; ++j) h0[j] = fmaf(v.z, W0[(16 + 2 * g) * 32 + j], h0[j]);
#pragma unroll
        for (int j = 0; j < 32; ++j) h0[j] = fmaf(v.w, W0[(17 + 2 * g) * 32 + j], h0[j]);
    }
#pragma unroll
    for (int j = 0; j < 32; ++j) h0[j] = (h0[j] >= 0.0f) ? h0[j] : 0.01f * h0[j];

    float h1[32];
#pragma unroll
    for (int j = 0; j < 32; ++j) h1[j] = b1[j];
#pragma unroll
    for (int i = 0; i < 32; ++i) {
        const float e = h0[i];
#pragma unroll
        for (int j = 0; j < 32; ++j) h1[j] = fmaf(e, W1[i * 32 + j], h1[j]);
    }
#pragma unroll
    for (int j = 0; j < 32; ++j) h1[j] = (h1[j] >= 0.0f) ? h1[j] : 0.01f * h1[j];

    float acc = b2[0];
#pragma unroll
    for (int j = 0; j < 32; ++j) acc = fmaf(h1[j], W2[j], acc);

    if (sc) {
        const float* scw = (const float*)sc;             // read only .w (4B)
        out[__float_as_int(scw[4 * (size_t)p + 3])] = acc;
    } else {
        out[p] = acc;
    }
}

// ---------------- Fallback: fused single kernel (r3 structure) ---------------
template<int L>
__device__ __forceinline__ void fuse_level(float x, float y, float z,
                                           const float* __restrict__ emb,
                                           float4 q0, float4 q1,
                                           float4 q2, float4 q3,
                                           float* __restrict__ h0,
                                           const float* __restrict__ W0)
{
    float a0, a1;
    lvl_finish<L>(x, y, z, emb, q0, q1, q2, q3, a0, a1);
#pragma unroll
    for (int j = 0; j < 32; ++j)
        h0[j] = fmaf(a0, W0[(2 * L + 0) * 32 + j], h0[j]);
#pragma unroll
    for (int j = 0; j < 32; ++j)
        h0[j] = fmaf(a1, W0[(2 * L + 1) * 32 + j], h0[j]);
}

__global__ __launch_bounds__(256, 4)
void fused_kernel(const float* __restrict__ coords,
                  const float* __restrict__ emb,
                  const float* __restrict__ W0, const float* __restrict__ b0,
                  const float* __restrict__ W1, const float* __restrict__ b1,
                  const float* __restrict__ W2, const float* __restrict__ b2,
                  float* __restrict__ out, int n)
{
    const int tid = blockIdx.x * blockDim.x + threadIdx.x;
    if (tid >= n) return;
    const float x = (coords[tid * 3 + 0] + 1.0f) * 0.5f;
    const float y = (coords[tid * 3 + 1] + 1.0f) * 0.5f;
    const float z = (coords[tid * 3 + 2] + 1.0f) * 0.5f;

    float h0[32];
#pragma unroll
    for (int j = 0; j < 32; ++j) h0[j] = b0[j];

    float4 a0, a1, a2, a3, b0r, b1r, b2r, b3r;
#define ISS_A(L) lvl_issue<L>(x, y, z, emb, a0, a1, a2, a3);
#define ISS_B(L) lvl_issue<L>(x, y, z, emb, b0r, b1r, b2r, b3r);
#define FUS_A(L) fuse_level<L>(x, y, z, emb, a0, a1, a2, a3, h0, W0);
#define FUS_B(L) fuse_level<L>(x, y, z, emb, b0r, b1r, b2r, b3r, h0, W0);
    ISS_A(0)
    ISS_B(1)  FUS_A(0)
    ISS_A(2)  FUS_B(1)
    ISS_B(3)  FUS_A(2)
    ISS_A(4)  FUS_B(3)
    ISS_B(5)  FUS_A(4)
    ISS_A(6)  FUS_B(5)
    ISS_B(7)  FUS_A(6)
    ISS_A(8)  FUS_B(7)
    ISS_B(9)  FUS_A(8)
    ISS_A(10) FUS_B(9)
    ISS_B(11) FUS_A(10)
    ISS_A(12) FUS_B(11)
    ISS_B(13) FUS_A(12)
    ISS_A(14) FUS_B(13)
    ISS_B(15) FUS_A(14)
    FUS_B(15)
#undef ISS_A
#undef ISS_B
#undef FUS_A
#undef FUS_B

#pragma unroll
    for (int j = 0; j < 32; ++j) h0[j] = (h0[j] >= 0.0f) ? h0[j] : 0.01f * h0[j];
    float h1[32];
#pragma unroll
    for (int j = 0; j < 32; ++j) h1[j] = b1[j];
#pragma unroll
    for (int i = 0; i < 32; ++i) {
        const float e = h0[i];
#pragma unroll
        for (int j = 0; j < 32; ++j) h1[j] = fmaf(e, W1[i * 32 + j], h1[j]);
    }
#pragma unroll
    for (int j = 0; j < 32; ++j) h1[j] = (h1[j] >= 0.0f) ? h1[j] : 0.01f * h1[j];
    float acc = b2[0];
#pragma unroll
    for (int j = 0; j < 32; ++j) acc = fmaf(h1[j], W2[j], acc);
    out[tid] = acc;
}

extern "C" void kernel_launch(void* const* d_in, const int* in_sizes, int n_in,
                              void* d_out, int out_size, void* d_ws, size_t ws_size,
                              hipStream_t stream) {
    const float* coords = (const float*)d_in[0];   // [N,1,3]
    const float* emb    = (const float*)d_in[1];   // [total,1,2]
    const float* W0     = (const float*)d_in[2];
    const float* b0     = (const float*)d_in[3];
    const float* W1     = (const float*)d_in[4];
    const float* b1     = (const float*)d_in[5];
    const float* W2     = (const float*)d_in[6];
    const float* b2     = (const float*)d_in[7];
    float* out = (float*)d_out;

    const int n = in_sizes[0] / 3;   // 262144
    const int nb = (n + 255) / 256;

    // ws layout: counts[32K] | offsets[32K] | sc float4[n] | enc float4[8n]
    char* base = (char*)d_ws;
    int*    counts  = (int*)base;
    int*    offsets = (int*)(base + NBUCKET * 4);
    float4* sc      = (float4*)(base + 2 * (size_t)NBUCKET * 4);
    float4* encws   = (float4*)(base + 2 * (size_t)NBUCKET * 4 + (size_t)n * 16);

    const size_t need_sorted = 2 * (size_t)NBUCKET * 4 + (size_t)n * 16
                             + (size_t)n * 128;                 // ~38.0 MB
    const size_t need_plain  = (size_t)n * 128;                 // 33.6 MB

    if (ws_size >= need_sorted) {
        hipMemsetAsync(counts, 0, NBUCKET * 4, stream);
        hist_kernel<<<nb, 256, 0, stream>>>(coords, counts, n);
        scan_kernel<<<1, 1024, 0, stream>>>(counts, offsets);
        scatter_kernel<<<nb, 256, 0, stream>>>(coords, offsets, sc, n);
        enc_sorted<<<nb * 8, 256, 0, stream>>>(sc, emb, encws, n);
        mlp_kernel<<<nb, 256, 0, stream>>>(encws, sc,
                                           W0, b0, W1, b1, W2, b2, out, n);
    } else if (ws_size >= need_plain) {
        float4* encp = (float4*)d_ws;
        enc_unsorted<<<nb * 8, 256, 0, stream>>>(coords, emb, encp, n);
        mlp_kernel<<<nb, 256, 0, stream>>>(encp, nullptr,
                                           W0, b0, W1, b1, W2, b2, out, n);
    } else {
        fused_kernel<<<nb, 256, 0, stream>>>(coords, emb,
                                             W0, b0, W1, b1, W2, b2, out, n);
    }
}

// Round 12
// 111.995 us; speedup vs baseline: 1.3425x; 1.3357x over previous
//
#include <hip/hip_runtime.h>

#define NLVL 16

// Per-level constants from the reference's _level_params() (f64 math -> f32).
constexpr float SCALEC[NLVL] = {
    15.0f, 19.15873679831797f, 24.39841683149119f, 31.0f,
    39.31747359663594f, 49.79683366298238f, 63.0f, 79.63494719327189f,
    100.59366732596477f, 127.0f, 160.26989438654376f, 202.18733465192954f,
    255.0f, 321.5397887730875f, 405.3746693038591f, 511.0f
};
constexpr int RESC[NLVL] = {
    16, 21, 26, 32, 41, 51, 64, 81, 102, 128, 162, 204, 256, 323, 407, 512
};
constexpr int OFFC[NLVL] = {
    0, 4096, 13360, 30936, 63704, 132632, 265288, 527432,
    1051720, 1576008, 2100296, 2624584, 3148872, 3673160, 4197448, 4721736
};
// Levels 0..6: lin (incl. corner offsets) < res^3 <= hsize -> mask is a no-op.
// Levels 7..15: hsize == 2^19 -> lin & 0x7FFFF; x-pair (e0,e0+1) wraps when
// e0 == 0x7FFFF -> cndmask fix with the level's entry 0 (uniform s_load).
constexpr int HMASK = 0x7FFFF;

#define NBUCKET 32768   // 5 bits/axis Morton over the occupied octant

// ---------------------------------------------------------------- gather core
template<int L>
__device__ __forceinline__ void lvl_issue(float x, float y, float z,
                                          const float* __restrict__ emb,
                                          float4& q0, float4& q1,
                                          float4& q2, float4& q3)
{
    constexpr float s  = SCALEC[L];
    constexpr int   r  = RESC[L];
    constexpr int   r2 = RESC[L] * RESC[L];
    constexpr int   off = OFFC[L];
    const float px = x * s, py = y * s, pz = z * s;
    const int lin = (int)floorf(px) + r * (int)floorf(py) + r2 * (int)floorf(pz);
    int i0 = lin, i1 = lin + r, i2 = lin + r2, i3 = lin + r2 + r;
    if constexpr (L >= 7) { i0 &= HMASK; i1 &= HMASK; i2 &= HMASK; i3 &= HMASK; }
    __builtin_memcpy(&q0, emb + 2 * (off + i0), 16);
    __builtin_memcpy(&q1, emb + 2 * (off + i1), 16);
    __builtin_memcpy(&q2, emb + 2 * (off + i2), 16);
    __builtin_memcpy(&q3, emb + 2 * (off + i3), 16);
}

template<int L>
__device__ __forceinline__ void lvl_finish(float x, float y, float z,
                                           const float* __restrict__ emb,
                                           float4 q0, float4 q1,
                                           float4 q2, float4 q3,
                                           float& a0, float& a1)
{
    constexpr float s  = SCALEC[L];
    constexpr int   r  = RESC[L];
    constexpr int   r2 = RESC[L] * RESC[L];
    constexpr int   off = OFFC[L];

    const float px = x * s, py = y * s, pz = z * s;
    const float tx = px - floorf(px), ty = py - floorf(py), tz = pz - floorf(pz);

    if constexpr (L >= 7) {
        const int lin = (int)floorf(px) + r * (int)floorf(py) + r2 * (int)floorf(pz);
        const int i0 = lin & HMASK, i1 = (lin + r) & HMASK;
        const int i2 = (lin + r2) & HMASK, i3 = (lin + r2 + r) & HMASK;
        const float f0x = emb[2 * off], f0y = emb[2 * off + 1];  // uniform s_load
        q0.z = (i0 == HMASK) ? f0x : q0.z;  q0.w = (i0 == HMASK) ? f0y : q0.w;
        q1.z = (i1 == HMASK) ? f0x : q1.z;  q1.w = (i1 == HMASK) ? f0y : q1.w;
        q2.z = (i2 == HMASK) ? f0x : q2.z;  q2.w = (i2 == HMASK) ? f0y : q2.w;
        q3.z = (i3 == HMASK) ? f0x : q3.z;  q3.w = (i3 == HMASK) ? f0y : q3.w;
    }

    const float wx1 = tx, wx0 = 1.0f - tx;
    const float wy1 = ty, wy0 = 1.0f - ty;
    const float wz1 = tz, wz0 = 1.0f - tz;
    const float w00 = wy0 * wz0, w10 = wy1 * wz0;
    const float w01 = wy0 * wz1, w11 = wy1 * wz1;
    float r0 = 0.0f, r1 = 0.0f;
    r0 = fmaf(w00 * wx0, q0.x, r0); r1 = fmaf(w00 * wx0, q0.y, r1);
    r0 = fmaf(w00 * wx1, q0.z, r0); r1 = fmaf(w00 * wx1, q0.w, r1);
    r0 = fmaf(w10 * wx0, q1.x, r0); r1 = fmaf(w10 * wx0, q1.y, r1);
    r0 = fmaf(w10 * wx1, q1.z, r0); r1 = fmaf(w10 * wx1, q1.w, r1);
    r0 = fmaf(w01 * wx0, q2.x, r0); r1 = fmaf(w01 * wx0, q2.y, r1);
    r0 = fmaf(w01 * wx1, q2.z, r0); r1 = fmaf(w01 * wx1, q2.w, r1);
    r0 = fmaf(w11 * wx0, q3.x, r0); r1 = fmaf(w11 * wx0, q3.y, r1);
    r0 = fmaf(w11 * wx1, q3.z, r0); r1 = fmaf(w11 * wx1, q3.w, r1);
    a0 = r0; a1 = r1;
}

// Pair {G, G+8} for one point -> packed float4 of 4 encoder channels.
template<int G>
__device__ __forceinline__ float4 enc_point(float x, float y, float z,
                                            const float* __restrict__ emb)
{
    float4 a0, a1, a2, a3, b0, b1, b2, b3;
    lvl_issue<G>(x, y, z, emb, a0, a1, a2, a3);
    lvl_issue<G + 8>(x, y, z, emb, b0, b1, b2, b3);
    float e0, e1, e2, e3;
    lvl_finish<G>(x, y, z, emb, a0, a1, a2, a3, e0, e1);
    lvl_finish<G + 8>(x, y, z, emb, b0, b1, b2, b3, e2, e3);
    return make_float4(e0, e1, e2, e3);
}

// ---------------------------------------------------------------- sort passes
__device__ __forceinline__ int bucket_key(float x, float y, float z)
{
    // x,y,z in [0.5,1) (inputs are (c+1)/2, c in [0,1)); clamp for safety.
    int kx = (int)((x * 2.0f - 1.0f) * 32.0f);
    int ky = (int)((y * 2.0f - 1.0f) * 32.0f);
    int kz = (int)((z * 2.0f - 1.0f) * 32.0f);
    kx = min(31, max(0, kx)); ky = min(31, max(0, ky)); kz = min(31, max(0, kz));
    int m = 0;
#pragma unroll
    for (int b = 0; b < 5; ++b) {
        m |= (((kx >> b) & 1) << (3 * b))
           | (((ky >> b) & 1) << (3 * b + 1))
           | (((kz >> b) & 1) << (3 * b + 2));
    }
    return m;
}

__global__ __launch_bounds__(256)
void hist_kernel(const float* __restrict__ coords, int* __restrict__ counts, int n)
{
    const int p = blockIdx.x * 256 + threadIdx.x;
    if (p >= n) return;
    const float x = (coords[p * 3 + 0] + 1.0f) * 0.5f;
    const float y = (coords[p * 3 + 1] + 1.0f) * 0.5f;
    const float z = (coords[p * 3 + 2] + 1.0f) * 0.5f;
    atomicAdd(&counts[bucket_key(x, y, z)], 1);
}

__global__ __launch_bounds__(1024)
void scan_kernel(const int* __restrict__ counts, int* __restrict__ offsets)
{
    __shared__ int part[1024];
    const int t = threadIdx.x;
    const int base = t * 32;                 // contiguous 32-bucket chunk
    int v[32];
    const int4* c4 = (const int4*)(counts + base);
#pragma unroll
    for (int i = 0; i < 8; ++i) {
        const int4 q = c4[i];
        v[4 * i] = q.x; v[4 * i + 1] = q.y; v[4 * i + 2] = q.z; v[4 * i + 3] = q.w;
    }
    int sum = 0;
#pragma unroll
    for (int i = 0; i < 32; ++i) sum += v[i];
    part[t] = sum;
    __syncthreads();
    for (int s = 1; s < 1024; s <<= 1) {     // Hillis-Steele inclusive scan
        const int pv = (t >= s) ? part[t - s] : 0;
        __syncthreads();
        part[t] += pv;
        __syncthreads();
    }
    int run = part[t] - sum;                 // exclusive prefix of this chunk
    int o[32];
#pragma unroll
    for (int i = 0; i < 32; ++i) { o[i] = run; run += v[i]; }
    int4* o4 = (int4*)(offsets + base);
#pragma unroll
    for (int i = 0; i < 8; ++i)
        o4[i] = make_int4(o[4 * i], o[4 * i + 1], o[4 * i + 2], o[4 * i + 3]);
}

__global__ __launch_bounds__(256)
void scatter_kernel(const float* __restrict__ coords, int* __restrict__ offsets,
                    float4* __restrict__ sc, int n)
{
    const int p = blockIdx.x * 256 + threadIdx.x;
    if (p >= n) return;
    const float x = (coords[p * 3 + 0] + 1.0f) * 0.5f;
    const float y = (coords[p * 3 + 1] + 1.0f) * 0.5f;
    const float z = (coords[p * 3 + 2] + 1.0f) * 0.5f;
    const int dst = atomicAdd(&offsets[bucket_key(x, y, z)], 1);
    sc[dst] = make_float4(x, y, z, __int_as_float(p));
}

// ---------------------------------------------------------------- pass 1: enc
// pair = blockIdx.x & 7: XCD-affine level-pair (r8: FETCH 103 -> 43 MB).
// Sorted input: a wave's 64 lanes are spatial neighbors -> corner loads
// share cache lines (L1/L2 hits) -> far fewer unique-line misses per wave.
__global__ __launch_bounds__(256)
void enc_sorted(const float4* __restrict__ sc, const float* __restrict__ emb,
                float4* __restrict__ encws, int n)
{
    const int pair = blockIdx.x & 7;
    const int q = (blockIdx.x >> 3) * 256 + threadIdx.x;
    if (q >= n) return;
    const float4 c = sc[q];
    switch (pair) {
        case 0: encws[(size_t)0 * n + q] = enc_point<0>(c.x, c.y, c.z, emb); break;
        case 1: encws[(size_t)1 * n + q] = enc_point<1>(c.x, c.y, c.z, emb); break;
        case 2: encws[(size_t)2 * n + q] = enc_point<2>(c.x, c.y, c.z, emb); break;
        case 3: encws[(size_t)3 * n + q] = enc_point<3>(c.x, c.y, c.z, emb); break;
        case 4: encws[(size_t)4 * n + q] = enc_point<4>(c.x, c.y, c.z, emb); break;
        case 5: encws[(size_t)5 * n + q] = enc_point<5>(c.x, c.y, c.z, emb); break;
        case 6: encws[(size_t)6 * n + q] = enc_point<6>(c.x, c.y, c.z, emb); break;
        default: encws[(size_t)7 * n + q] = enc_point<7>(c.x, c.y, c.z, emb); break;
    }
}

__global__ __launch_bounds__(256)
void enc_unsorted(const float* __restrict__ coords, const float* __restrict__ emb,
                  float4* __restrict__ encws, int n)
{
    const int pair = blockIdx.x & 7;
    const int q = (blockIdx.x >> 3) * 256 + threadIdx.x;
    if (q >= n) return;
    const float x = (coords[q * 3 + 0] + 1.0f) * 0.5f;
    const float y = (coords[q * 3 + 1] + 1.0f) * 0.5f;
    const float z = (coords[q * 3 + 2] + 1.0f) * 0.5f;
    switch (pair) {
        case 0: encws[(size_t)0 * n + q] = enc_point<0>(x, y, z, emb); break;
        case 1: encws[(size_t)1 * n + q] = enc_point<1>(x, y, z, emb); break;
        case 2: encws[(size_t)2 * n + q] = enc_point<2>(x, y, z, emb); break;
        case 3: encws[(size_t)3 * n + q] = enc_point<3>(x, y, z, emb); break;
        case 4: encws[(size_t)4 * n + q] = enc_point<4>(x, y, z, emb); break;
        case 5: encws[(size_t)5 * n + q] = enc_point<5>(x, y, z, emb); break;
        case 6: encws[(size_t)6 * n + q] = enc_point<6>(x, y, z, emb); break;
        default: encws[(size_t)7 * n + q] = enc_point<7>(x, y, z, emb); break;
    }
}

// ---------------------------------------------------------------- pass 2: MLP
// EXACT r9-proven body (no spill, ~16us). Output goes to dst[p*stride]:
// sorted path  -> dst = &sc[0].x, stride 4 (acc overwrites dead sc.x field)
// fallback     -> dst = out,      stride 1
// No load feeds the store address; no branch in the tail.
__global__ __launch_bounds__(256)
void mlp_kernel(const float4* __restrict__ encws,
                const float* __restrict__ W0, const float* __restrict__ b0,
                const float* __restrict__ W1, const float* __restrict__ b1,
                const float* __restrict__ W2, const float* __restrict__ b2,
                float* __restrict__ dst, int stride, int n)
{
    const int p = blockIdx.x * 256 + threadIdx.x;
    if (p >= n) return;

    float enc[32];
#pragma unroll
    for (int g = 0; g < 8; ++g) {                       // 8 coalesced 16B loads
        const float4 v = encws[(size_t)g * n + p];
        enc[2 * g + 0]       = v.x;
        enc[2 * g + 1]       = v.y;
        enc[2 * (g + 8) + 0] = v.z;
        enc[2 * (g + 8) + 1] = v.w;
    }

    float h0[32];
#pragma unroll
    for (int j = 0; j < 32; ++j) h0[j] = b0[j];
#pragma unroll
    for (int i = 0; i < 32; ++i) {
        const float e = enc[i];
#pragma unroll
        for (int j = 0; j < 32; ++j) h0[j] = fmaf(e, W0[i * 32 + j], h0[j]);
    }
#pragma unroll
    for (int j = 0; j < 32; ++j) h0[j] = (h0[j] >= 0.0f) ? h0[j] : 0.01f * h0[j];

    float h1[32];
#pragma unroll
    for (int j = 0; j < 32; ++j) h1[j] = b1[j];
#pragma unroll
    for (int i = 0; i < 32; ++i) {
        const float e = h0[i];
#pragma unroll
        for (int j = 0; j < 32; ++j) h1[j] = fmaf(e, W1[i * 32 + j], h1[j]);
    }
#pragma unroll
    for (int j = 0; j < 32; ++j) h1[j] = (h1[j] >= 0.0f) ? h1[j] : 0.01f * h1[j];

    float acc = b2[0];
#pragma unroll
    for (int j = 0; j < 32; ++j) acc = fmaf(h1[j], W2[j], acc);

    dst[(size_t)p * stride] = acc;
}

// ---------------------------------------------------------------- unsort
// Tiny permute: acc sits in sc[p].x, original index in sc[p].w.
__global__ __launch_bounds__(256)
void unsort_kernel(const float4* __restrict__ sc, float* __restrict__ out, int n)
{
    const int p = blockIdx.x * 256 + threadIdx.x;
    if (p >= n) return;
    const float4 v = sc[p];                 // coalesced 16B read
    out[__float_as_int(v.w)] = v.x;         // scattered 4B write
}

// ---------------- Fallback: fused single kernel (r3 structure) ---------------
template<int L>
__device__ __forceinline__ void fuse_level(float x, float y, float z,
                                           const float* __restrict__ emb,
                                           float4 q0, float4 q1,
                                           float4 q2, float4 q3,
                                           float* __restrict__ h0,
                                           const float* __restrict__ W0)
{
    float a0, a1;
    lvl_finish<L>(x, y, z, emb, q0, q1, q2, q3, a0, a1);
#pragma unroll
    for (int j = 0; j < 32; ++j)
        h0[j] = fmaf(a0, W0[(2 * L + 0) * 32 + j], h0[j]);
#pragma unroll
    for (int j = 0; j < 32; ++j)
        h0[j] = fmaf(a1, W0[(2 * L + 1) * 32 + j], h0[j]);
}

__global__ __launch_bounds__(256, 4)
void fused_kernel(const float* __restrict__ coords,
                  const float* __restrict__ emb,
                  const float* __restrict__ W0, const float* __restrict__ b0,
                  const float* __restrict__ W1, const float* __restrict__ b1,
                  const float* __restrict__ W2, const float* __restrict__ b2,
                  float* __restrict__ out, int n)
{
    const int tid = blockIdx.x * blockDim.x + threadIdx.x;
    if (tid >= n) return;
    const float x = (coords[tid * 3 + 0] + 1.0f) * 0.5f;
    const float y = (coords[tid * 3 + 1] + 1.0f) * 0.5f;
    const float z = (coords[tid * 3 + 2] + 1.0f) * 0.5f;

    float h0[32];
#pragma unroll
    for (int j = 0; j < 32; ++j) h0[j] = b0[j];

    float4 a0, a1, a2, a3, b0r, b1r, b2r, b3r;
#define ISS_A(L) lvl_issue<L>(x, y, z, emb, a0, a1, a2, a3);
#define ISS_B(L) lvl_issue<L>(x, y, z, emb, b0r, b1r, b2r, b3r);
#define FUS_A(L) fuse_level<L>(x, y, z, emb, a0, a1, a2, a3, h0, W0);
#define FUS_B(L) fuse_level<L>(x, y, z, emb, b0r, b1r, b2r, b3r, h0, W0);
    ISS_A(0)
    ISS_B(1)  FUS_A(0)
    ISS_A(2)  FUS_B(1)
    ISS_B(3)  FUS_A(2)
    ISS_A(4)  FUS_B(3)
    ISS_B(5)  FUS_A(4)
    ISS_A(6)  FUS_B(5)
    ISS_B(7)  FUS_A(6)
    ISS_A(8)  FUS_B(7)
    ISS_B(9)  FUS_A(8)
    ISS_A(10) FUS_B(9)
    ISS_B(11) FUS_A(10)
    ISS_A(12) FUS_B(11)
    ISS_B(13) FUS_A(12)
    ISS_A(14) FUS_B(13)
    ISS_B(15) FUS_A(14)
    FUS_B(15)
#undef ISS_A
#undef ISS_B
#undef FUS_A
#undef FUS_B

#pragma unroll
    for (int j = 0; j < 32; ++j) h0[j] = (h0[j] >= 0.0f) ? h0[j] : 0.01f * h0[j];
    float h1[32];
#pragma unroll
    for (int j = 0; j < 32; ++j) h1[j] = b1[j];
#pragma unroll
    for (int i = 0; i < 32; ++i) {
        const float e = h0[i];
#pragma unroll
        for (int j = 0; j < 32; ++j) h1[j] = fmaf(e, W1[i * 32 + j], h1[j]);
    }
#pragma unroll
    for (int j = 0; j < 32; ++j) h1[j] = (h1[j] >= 0.0f) ? h1[j] : 0.01f * h1[j];
    float acc = b2[0];
#pragma unroll
    for (int j = 0; j < 32; ++j) acc = fmaf(h1[j], W2[j], acc);
    out[tid] = acc;
}

extern "C" void kernel_launch(void* const* d_in, const int* in_sizes, int n_in,
                              void* d_out, int out_size, void* d_ws, size_t ws_size,
                              hipStream_t stream) {
    const float* coords = (const float*)d_in[0];   // [N,1,3]
    const float* emb    = (const float*)d_in[1];   // [total,1,2]
    const float* W0     = (const float*)d_in[2];
    const float* b0     = (const float*)d_in[3];
    const float* W1     = (const float*)d_in[4];
    const float* b1     = (const float*)d_in[5];
    const float* W2     = (const float*)d_in[6];
    const float* b2     = (const float*)d_in[7];
    float* out = (float*)d_out;

    const int n = in_sizes[0] / 3;   // 262144
    const int nb = (n + 255) / 256;

    // ws layout: counts[32K] | offsets[32K] | sc float4[n] | enc float4[8n]
    char* base = (char*)d_ws;
    int*    counts  = (int*)base;
    int*    offsets = (int*)(base + NBUCKET * 4);
    float4* sc      = (float4*)(base + 2 * (size_t)NBUCKET * 4);
    float4* encws   = (float4*)(base + 2 * (size_t)NBUCKET * 4 + (size_t)n * 16);

    const size_t need_sorted = 2 * (size_t)NBUCKET * 4 + (size_t)n * 16
                             + (size_t)n * 128;                 // ~38.0 MB
    const size_t need_plain  = (size_t)n * 128;                 // 33.6 MB

    if (ws_size >= need_sorted) {
        hipMemsetAsync(counts, 0, NBUCKET * 4, stream);
        hist_kernel<<<nb, 256, 0, stream>>>(coords, counts, n);
        scan_kernel<<<1, 1024, 0, stream>>>(counts, offsets);
        scatter_kernel<<<nb, 256, 0, stream>>>(coords, offsets, sc, n);
        enc_sorted<<<nb * 8, 256, 0, stream>>>(sc, emb, encws, n);
        mlp_kernel<<<nb, 256, 0, stream>>>(encws,
                                           W0, b0, W1, b1, W2, b2,
                                           (float*)sc, 4, n);   // acc -> sc[p].x
        unsort_kernel<<<nb, 256, 0, stream>>>(sc, out, n);
    } else if (ws_size >= need_plain) {
        float4* encp = (float4*)d_ws;
        enc_unsorted<<<nb * 8, 256, 0, stream>>>(coords, emb, encp, n);
        mlp_kernel<<<nb, 256, 0, stream>>>(encp,
                                           W0, b0, W1, b1, W2, b2,
                                           out, 1, n);
    } else {
        fused_kernel<<<nb, 256, 0, stream>>>(coords, emb,
                                             W0, b0, W1, b1, W2, b2, out, n);
    }
}

// Round 13
// 110.259 us; speedup vs baseline: 1.3636x; 1.0157x over previous
//
#include <hip/hip_runtime.h>

typedef __attribute__((ext_vector_type(4))) float f32x4;

#define NLVL 16

// Per-level constants from the reference's _level_params() (f64 math -> f32).
constexpr float SCALEC[NLVL] = {
    15.0f, 19.15873679831797f, 24.39841683149119f, 31.0f,
    39.31747359663594f, 49.79683366298238f, 63.0f, 79.63494719327189f,
    100.59366732596477f, 127.0f, 160.26989438654376f, 202.18733465192954f,
    255.0f, 321.5397887730875f, 405.3746693038591f, 511.0f
};
constexpr int RESC[NLVL] = {
    16, 21, 26, 32, 41, 51, 64, 81, 102, 128, 162, 204, 256, 323, 407, 512
};
constexpr int OFFC[NLVL] = {
    0, 4096, 13360, 30936, 63704, 132632, 265288, 527432,
    1051720, 1576008, 2100296, 2624584, 3148872, 3673160, 4197448, 4721736
};
// Levels 0..6: lin (incl. corner offsets) < res^3 <= hsize -> mask is a no-op.
// Levels 7..15: hsize == 2^19 -> lin & 0x7FFFF; x-pair (e0,e0+1) wraps when
// e0 == 0x7FFFF -> cndmask fix with the level's entry 0 (uniform s_load).
constexpr int HMASK = 0x7FFFF;

#define NBUCKET 32768   // 5 bits/axis Morton over the occupied octant

// ------------------------------------------------------------- issue variants
// asm-pinned: compiler cannot sink these past the consumer, so all stay in
// flight until the counted s_waitcnt. Safe here: no big arrays to spill.
template<int L>
__device__ __forceinline__ void lvl_issue_asm(float x, float y, float z,
                                              const float* __restrict__ emb,
                                              f32x4& q0, f32x4& q1,
                                              f32x4& q2, f32x4& q3)
{
    constexpr float s  = SCALEC[L];
    constexpr int   r  = RESC[L];
    constexpr int   r2 = RESC[L] * RESC[L];
    constexpr int   off = OFFC[L];
    const float px = x * s, py = y * s, pz = z * s;
    const int lin = (int)floorf(px) + r * (int)floorf(py) + r2 * (int)floorf(pz);
    int i0 = lin, i1 = lin + r, i2 = lin + r2, i3 = lin + r2 + r;
    if constexpr (L >= 7) { i0 &= HMASK; i1 &= HMASK; i2 &= HMASK; i3 &= HMASK; }
    const float* p0 = emb + 2 * (off + i0);
    const float* p1 = emb + 2 * (off + i1);
    const float* p2 = emb + 2 * (off + i2);
    const float* p3 = emb + 2 * (off + i3);
    asm volatile("global_load_dwordx4 %0, %1, off" : "=v"(q0) : "v"(p0));
    asm volatile("global_load_dwordx4 %0, %1, off" : "=v"(q1) : "v"(p1));
    asm volatile("global_load_dwordx4 %0, %1, off" : "=v"(q2) : "v"(p2));
    asm volatile("global_load_dwordx4 %0, %1, off" : "=v"(q3) : "v"(p3));
}

template<int L>
__device__ __forceinline__ void lvl_issue_plain(float x, float y, float z,
                                                const float* __restrict__ emb,
                                                f32x4& q0, f32x4& q1,
                                                f32x4& q2, f32x4& q3)
{
    constexpr float s  = SCALEC[L];
    constexpr int   r  = RESC[L];
    constexpr int   r2 = RESC[L] * RESC[L];
    constexpr int   off = OFFC[L];
    const float px = x * s, py = y * s, pz = z * s;
    const int lin = (int)floorf(px) + r * (int)floorf(py) + r2 * (int)floorf(pz);
    int i0 = lin, i1 = lin + r, i2 = lin + r2, i3 = lin + r2 + r;
    if constexpr (L >= 7) { i0 &= HMASK; i1 &= HMASK; i2 &= HMASK; i3 &= HMASK; }
    __builtin_memcpy(&q0, emb + 2 * (off + i0), 16);
    __builtin_memcpy(&q1, emb + 2 * (off + i1), 16);
    __builtin_memcpy(&q2, emb + 2 * (off + i2), 16);
    __builtin_memcpy(&q3, emb + 2 * (off + i3), 16);
}

// Finish level L: rare-wrap fix, trilinear weights, reduce to (a0, a1).
template<int L>
__device__ __forceinline__ void lvl_finish(float x, float y, float z,
                                           const float* __restrict__ emb,
                                           f32x4 q0, f32x4 q1,
                                           f32x4 q2, f32x4 q3,
                                           float& a0, float& a1)
{
    constexpr float s  = SCALEC[L];
    constexpr int   r  = RESC[L];
    constexpr int   r2 = RESC[L] * RESC[L];
    constexpr int   off = OFFC[L];

    const float px = x * s, py = y * s, pz = z * s;
    const float tx = px - floorf(px), ty = py - floorf(py), tz = pz - floorf(pz);

    if constexpr (L >= 7) {
        const int lin = (int)floorf(px) + r * (int)floorf(py) + r2 * (int)floorf(pz);
        const int i0 = lin & HMASK, i1 = (lin + r) & HMASK;
        const int i2 = (lin + r2) & HMASK, i3 = (lin + r2 + r) & HMASK;
        const float f0x = emb[2 * off], f0y = emb[2 * off + 1];  // uniform s_load
        q0.z = (i0 == HMASK) ? f0x : q0.z;  q0.w = (i0 == HMASK) ? f0y : q0.w;
        q1.z = (i1 == HMASK) ? f0x : q1.z;  q1.w = (i1 == HMASK) ? f0y : q1.w;
        q2.z = (i2 == HMASK) ? f0x : q2.z;  q2.w = (i2 == HMASK) ? f0y : q2.w;
        q3.z = (i3 == HMASK) ? f0x : q3.z;  q3.w = (i3 == HMASK) ? f0y : q3.w;
    }

    const float wx1 = tx, wx0 = 1.0f - tx;
    const float wy1 = ty, wy0 = 1.0f - ty;
    const float wz1 = tz, wz0 = 1.0f - tz;
    const float w00 = wy0 * wz0, w10 = wy1 * wz0;
    const float w01 = wy0 * wz1, w11 = wy1 * wz1;
    float r0 = 0.0f, r1 = 0.0f;
    r0 = fmaf(w00 * wx0, q0.x, r0); r1 = fmaf(w00 * wx0, q0.y, r1);
    r0 = fmaf(w00 * wx1, q0.z, r0); r1 = fmaf(w00 * wx1, q0.w, r1);
    r0 = fmaf(w10 * wx0, q1.x, r0); r1 = fmaf(w10 * wx0, q1.y, r1);
    r0 = fmaf(w10 * wx1, q1.z, r0); r1 = fmaf(w10 * wx1, q1.w, r1);
    r0 = fmaf(w01 * wx0, q2.x, r0); r1 = fmaf(w01 * wx0, q2.y, r1);
    r0 = fmaf(w01 * wx1, q2.z, r0); r1 = fmaf(w01 * wx1, q2.w, r1);
    r0 = fmaf(w11 * wx0, q3.x, r0); r1 = fmaf(w11 * wx0, q3.y, r1);
    r0 = fmaf(w11 * wx1, q3.z, r0); r1 = fmaf(w11 * wx1, q3.w, r1);
    a0 = r0; a1 = r1;
}

// asm-pipelined pair {G, G+8}: 8 loads in flight, two counted waits.
template<int G>
__device__ __forceinline__ void enc_one_asm(int q, float x, float y, float z,
                                            const float* __restrict__ emb,
                                            float4* __restrict__ encws, int n)
{
    f32x4 a0, a1, a2, a3, b0, b1, b2, b3;
    lvl_issue_asm<G>(x, y, z, emb, a0, a1, a2, a3);
    lvl_issue_asm<G + 8>(x, y, z, emb, b0, b1, b2, b3);

    float e0, e1, e2, e3;
    asm volatile("s_waitcnt vmcnt(4)" ::: "memory");
    __builtin_amdgcn_sched_barrier(0);
    lvl_finish<G>(x, y, z, emb, a0, a1, a2, a3, e0, e1);
    asm volatile("s_waitcnt vmcnt(0)" ::: "memory");
    __builtin_amdgcn_sched_barrier(0);
    lvl_finish<G + 8>(x, y, z, emb, b0, b1, b2, b3, e2, e3);

    encws[(size_t)G * n + q] = make_float4(e0, e1, e2, e3);
}

// plain pair (fallback / unsorted path)
template<int G>
__device__ __forceinline__ float4 enc_point(float x, float y, float z,
                                            const float* __restrict__ emb)
{
    f32x4 a0, a1, a2, a3, b0, b1, b2, b3;
    lvl_issue_plain<G>(x, y, z, emb, a0, a1, a2, a3);
    lvl_issue_plain<G + 8>(x, y, z, emb, b0, b1, b2, b3);
    float e0, e1, e2, e3;
    lvl_finish<G>(x, y, z, emb, a0, a1, a2, a3, e0, e1);
    lvl_finish<G + 8>(x, y, z, emb, b0, b1, b2, b3, e2, e3);
    return make_float4(e0, e1, e2, e3);
}

// ---------------------------------------------------------------- sort passes
__device__ __forceinline__ int bucket_key(float x, float y, float z)
{
    // x,y,z in [0.5,1) (inputs are (c+1)/2, c in [0,1)); clamp for safety.
    int kx = (int)((x * 2.0f - 1.0f) * 32.0f);
    int ky = (int)((y * 2.0f - 1.0f) * 32.0f);
    int kz = (int)((z * 2.0f - 1.0f) * 32.0f);
    kx = min(31, max(0, kx)); ky = min(31, max(0, ky)); kz = min(31, max(0, kz));
    int m = 0;
#pragma unroll
    for (int b = 0; b < 5; ++b) {
        m |= (((kx >> b) & 1) << (3 * b))
           | (((ky >> b) & 1) << (3 * b + 1))
           | (((kz >> b) & 1) << (3 * b + 2));
    }
    return m;
}

__global__ __launch_bounds__(256)
void hist_kernel(const float* __restrict__ coords, int* __restrict__ counts, int n)
{
    const int p = blockIdx.x * 256 + threadIdx.x;
    if (p >= n) return;
    const float x = (coords[p * 3 + 0] + 1.0f) * 0.5f;
    const float y = (coords[p * 3 + 1] + 1.0f) * 0.5f;
    const float z = (coords[p * 3 + 2] + 1.0f) * 0.5f;
    atomicAdd(&counts[bucket_key(x, y, z)], 1);
}

__global__ __launch_bounds__(1024)
void scan_kernel(const int* __restrict__ counts, int* __restrict__ offsets)
{
    __shared__ int part[1024];
    const int t = threadIdx.x;
    const int base = t * 32;                 // contiguous 32-bucket chunk
    int v[32];
    const int4* c4 = (const int4*)(counts + base);
#pragma unroll
    for (int i = 0; i < 8; ++i) {
        const int4 q = c4[i];
        v[4 * i] = q.x; v[4 * i + 1] = q.y; v[4 * i + 2] = q.z; v[4 * i + 3] = q.w;
    }
    int sum = 0;
#pragma unroll
    for (int i = 0; i < 32; ++i) sum += v[i];
    part[t] = sum;
    __syncthreads();
    for (int s = 1; s < 1024; s <<= 1) {     // Hillis-Steele inclusive scan
        const int pv = (t >= s) ? part[t - s] : 0;
        __syncthreads();
        part[t] += pv;
        __syncthreads();
    }
    int run = part[t] - sum;                 // exclusive prefix of this chunk
    int o[32];
#pragma unroll
    for (int i = 0; i < 32; ++i) { o[i] = run; run += v[i]; }
    int4* o4 = (int4*)(offsets + base);
#pragma unroll
    for (int i = 0; i < 8; ++i)
        o4[i] = make_int4(o[4 * i], o[4 * i + 1], o[4 * i + 2], o[4 * i + 3]);
}

__global__ __launch_bounds__(256)
void scatter_kernel(const float* __restrict__ coords, int* __restrict__ offsets,
                    float4* __restrict__ sc, int n)
{
    const int p = blockIdx.x * 256 + threadIdx.x;
    if (p >= n) return;
    const float x = (coords[p * 3 + 0] + 1.0f) * 0.5f;
    const float y = (coords[p * 3 + 1] + 1.0f) * 0.5f;
    const float z = (coords[p * 3 + 2] + 1.0f) * 0.5f;
    const int dst = atomicAdd(&offsets[bucket_key(x, y, z)], 1);
    sc[dst] = make_float4(x, y, z, __int_as_float(p));
}

// ---------------------------------------------------------------- pass 1: enc
// pair = blockIdx.x & 7: XCD-affine level-pair. Sorted input: 64 lanes are
// spatial neighbors -> corner loads share cache lines. asm-pinned loads keep
// 8 requests in flight per thread (compiler left only ~2 at VGPR=32 in r12).
__global__ __launch_bounds__(256)
void enc_sorted(const float4* __restrict__ sc, const float* __restrict__ emb,
                float4* __restrict__ encws, int n)
{
    const int pair = blockIdx.x & 7;
    const int q = (blockIdx.x >> 3) * 256 + threadIdx.x;
    if (q >= n) return;
    const float4 c = sc[q];
    switch (pair) {
        case 0: enc_one_asm<0>(q, c.x, c.y, c.z, emb, encws, n); break;
        case 1: enc_one_asm<1>(q, c.x, c.y, c.z, emb, encws, n); break;
        case 2: enc_one_asm<2>(q, c.x, c.y, c.z, emb, encws, n); break;
        case 3: enc_one_asm<3>(q, c.x, c.y, c.z, emb, encws, n); break;
        case 4: enc_one_asm<4>(q, c.x, c.y, c.z, emb, encws, n); break;
        case 5: enc_one_asm<5>(q, c.x, c.y, c.z, emb, encws, n); break;
        case 6: enc_one_asm<6>(q, c.x, c.y, c.z, emb, encws, n); break;
        default: enc_one_asm<7>(q, c.x, c.y, c.z, emb, encws, n); break;
    }
}

__global__ __launch_bounds__(256)
void enc_unsorted(const float* __restrict__ coords, const float* __restrict__ emb,
                  float4* __restrict__ encws, int n)
{
    const int pair = blockIdx.x & 7;
    const int q = (blockIdx.x >> 3) * 256 + threadIdx.x;
    if (q >= n) return;
    const float x = (coords[q * 3 + 0] + 1.0f) * 0.5f;
    const float y = (coords[q * 3 + 1] + 1.0f) * 0.5f;
    const float z = (coords[q * 3 + 2] + 1.0f) * 0.5f;
    switch (pair) {
        case 0: encws[(size_t)0 * n + q] = enc_point<0>(x, y, z, emb); break;
        case 1: encws[(size_t)1 * n + q] = enc_point<1>(x, y, z, emb); break;
        case 2: encws[(size_t)2 * n + q] = enc_point<2>(x, y, z, emb); break;
        case 3: encws[(size_t)3 * n + q] = enc_point<3>(x, y, z, emb); break;
        case 4: encws[(size_t)4 * n + q] = enc_point<4>(x, y, z, emb); break;
        case 5: encws[(size_t)5 * n + q] = enc_point<5>(x, y, z, emb); break;
        case 6: encws[(size_t)6 * n + q] = enc_point<6>(x, y, z, emb); break;
        default: encws[(size_t)7 * n + q] = enc_point<7>(x, y, z, emb); break;
    }
}

// ---------------------------------------------------------------- pass 2: MLP
// r9/r12-proven body (no spill, ~16us). Store to dst[p*stride]: sorted path
// overwrites dead sc[p].x (stride 4); fallback writes out[p] (stride 1).
__global__ __launch_bounds__(256)
void mlp_kernel(const float4* __restrict__ encws,
                const float* __restrict__ W0, const float* __restrict__ b0,
                const float* __restrict__ W1, const float* __restrict__ b1,
                const float* __restrict__ W2, const float* __restrict__ b2,
                float* __restrict__ dst, int stride, int n)
{
    const int p = blockIdx.x * 256 + threadIdx.x;
    if (p >= n) return;

    float enc[32];
#pragma unroll
    for (int g = 0; g < 8; ++g) {                       // 8 coalesced 16B loads
        const float4 v = encws[(size_t)g * n + p];
        enc[2 * g + 0]       = v.x;
        enc[2 * g + 1]       = v.y;
        enc[2 * (g + 8) + 0] = v.z;
        enc[2 * (g + 8) + 1] = v.w;
    }

    float h0[32];
#pragma unroll
    for (int j = 0; j < 32; ++j) h0[j] = b0[j];
#pragma unroll
    for (int i = 0; i < 32; ++i) {
        const float e = enc[i];
#pragma unroll
        for (int j = 0; j < 32; ++j) h0[j] = fmaf(e, W0[i * 32 + j], h0[j]);
    }
#pragma unroll
    for (int j = 0; j < 32; ++j) h0[j] = (h0[j] >= 0.0f) ? h0[j] : 0.01f * h0[j];

    float h1[32];
#pragma unroll
    for (int j = 0; j < 32; ++j) h1[j] = b1[j];
#pragma unroll
    for (int i = 0; i < 32; ++i) {
        const float e = h0[i];
#pragma unroll
        for (int j = 0; j < 32; ++j) h1[j] = fmaf(e, W1[i * 32 + j], h1[j]);
    }
#pragma unroll
    for (int j = 0; j < 32; ++j) h1[j] = (h1[j] >= 0.0f) ? h1[j] : 0.01f * h1[j];

    float acc = b2[0];
#pragma unroll
    for (int j = 0; j < 32; ++j) acc = fmaf(h1[j], W2[j], acc);

    dst[(size_t)p * stride] = acc;
}

// ---------------------------------------------------------------- unsort
__global__ __launch_bounds__(256)
void unsort_kernel(const float4* __restrict__ sc, float* __restrict__ out, int n)
{
    const int p = blockIdx.x * 256 + threadIdx.x;
    if (p >= n) return;
    const float4 v = sc[p];                 // coalesced 16B read
    out[__float_as_int(v.w)] = v.x;         // scattered 4B write
}

// ---------------- Fallback: fused single kernel (r3 structure) ---------------
template<int L>
__device__ __forceinline__ void fuse_level(float x, float y, float z,
                                           const float* __restrict__ emb,
                                           f32x4 q0, f32x4 q1,
                                           f32x4 q2, f32x4 q3,
                                           float* __restrict__ h0,
                                           const float* __restrict__ W0)
{
    float a0, a1;
    lvl_finish<L>(x, y, z, emb, q0, q1, q2, q3, a0, a1);
#pragma unroll
    for (int j = 0; j < 32; ++j)
        h0[j] = fmaf(a0, W0[(2 * L + 0) * 32 + j], h0[j]);
#pragma unroll
    for (int j = 0; j < 32; ++j)
        h0[j] = fmaf(a1, W0[(2 * L + 1) * 32 + j], h0[j]);
}

__global__ __launch_bounds__(256, 4)
void fused_kernel(const float* __restrict__ coords,
                  const float* __restrict__ emb,
                  const float* __restrict__ W0, const float* __restrict__ b0,
                  const float* __restrict__ W1, const float* __restrict__ b1,
                  const float* __restrict__ W2, const float* __restrict__ b2,
                  float* __restrict__ out, int n)
{
    const int tid = blockIdx.x * blockDim.x + threadIdx.x;
    if (tid >= n) return;
    const float x = (coords[tid * 3 + 0] + 1.0f) * 0.5f;
    const float y = (coords[tid * 3 + 1] + 1.0f) * 0.5f;
    const float z = (coords[tid * 3 + 2] + 1.0f) * 0.5f;

    float h0[32];
#pragma unroll
    for (int j = 0; j < 32; ++j) h0[j] = b0[j];

    f32x4 a0, a1, a2, a3, b0r, b1r, b2r, b3r;
#define ISS_A(L) lvl_issue_plain<L>(x, y, z, emb, a0, a1, a2, a3);
#define ISS_B(L) lvl_issue_plain<L>(x, y, z, emb, b0r, b1r, b2r, b3r);
#define FUS_A(L) fuse_level<L>(x, y, z, emb, a0, a1, a2, a3, h0, W0);
#define FUS_B(L) fuse_level<L>(x, y, z, emb, b0r, b1r, b2r, b3r, h0, W0);
    ISS_A(0)
    ISS_B(1)  FUS_A(0)
    ISS_A(2)  FUS_B(1)
    ISS_B(3)  FUS_A(2)
    ISS_A(4)  FUS_B(3)
    ISS_B(5)  FUS_A(4)
    ISS_A(6)  FUS_B(5)
    ISS_B(7)  FUS_A(6)
    ISS_A(8)  FUS_B(7)
    ISS_B(9)  FUS_A(8)
    ISS_A(10) FUS_B(9)
    ISS_B(11) FUS_A(10)
    ISS_A(12) FUS_B(11)
    ISS_B(13) FUS_A(12)
    ISS_A(14) FUS_B(13)
    ISS_B(15) FUS_A(14)
    FUS_B(15)
#undef ISS_A
#undef ISS_B
#undef FUS_A
#undef FUS_B

#pragma unroll
    for (int j = 0; j < 32; ++j) h0[j] = (h0[j] >= 0.0f) ? h0[j] : 0.01f * h0[j];
    float h1[32];
#pragma unroll
    for (int j = 0; j < 32; ++j) h1[j] = b1[j];
#pragma unroll
    for (int i = 0; i < 32; ++i) {
        const float e = h0[i];
#pragma unroll
        for (int j = 0; j < 32; ++j) h1[j] = fmaf(e, W1[i * 32 + j], h1[j]);
    }
#pragma unroll
    for (int j = 0; j < 32; ++j) h1[j] = (h1[j] >= 0.0f) ? h1[j] : 0.01f * h1[j];
    float acc = b2[0];
#pragma unroll
    for (int j = 0; j < 32; ++j) acc = fmaf(h1[j], W2[j], acc);
    out[tid] = acc;
}

extern "C" void kernel_launch(void* const* d_in, const int* in_sizes, int n_in,
                              void* d_out, int out_size, void* d_ws, size_t ws_size,
                              hipStream_t stream) {
    const float* coords = (const float*)d_in[0];   // [N,1,3]
    const float* emb    = (const float*)d_in[1];   // [total,1,2]
    const float* W0     = (const float*)d_in[2];
    const float* b0     = (const float*)d_in[3];
    const float* W1     = (const float*)d_in[4];
    const float* b1     = (const float*)d_in[5];
    const float* W2     = (const float*)d_in[6];
    const float* b2     = (const float*)d_in[7];
    float* out = (float*)d_out;

    const int n = in_sizes[0] / 3;   // 262144
    const int nb = (n + 255) / 256;

    // ws layout: counts[32K] | offsets[32K] | sc float4[n] | enc float4[8n]
    char* base = (char*)d_ws;
    int*    counts  = (int*)base;
    int*    offsets = (int*)(base + NBUCKET * 4);
    float4* sc      = (float4*)(base + 2 * (size_t)NBUCKET * 4);
    float4* encws   = (float4*)(base + 2 * (size_t)NBUCKET * 4 + (size_t)n * 16);

    const size_t need_sorted = 2 * (size_t)NBUCKET * 4 + (size_t)n * 16
                             + (size_t)n * 128;                 // ~38.0 MB
    const size_t need_plain  = (size_t)n * 128;                 // 33.6 MB

    if (ws_size >= need_sorted) {
        hipMemsetAsync(counts, 0, NBUCKET * 4, stream);
        hist_kernel<<<nb, 256, 0, stream>>>(coords, counts, n);
        scan_kernel<<<1, 1024, 0, stream>>>(counts, offsets);
        scatter_kernel<<<nb, 256, 0, stream>>>(coords, offsets, sc, n);
        enc_sorted<<<nb * 8, 256, 0, stream>>>(sc, emb, encws, n);
        mlp_kernel<<<nb, 256, 0, stream>>>(encws,
                                           W0, b0, W1, b1, W2, b2,
                                           (float*)sc, 4, n);   // acc -> sc[p].x
        unsort_kernel<<<nb, 256, 0, stream>>>(sc, out, n);
    } else if (ws_size >= need_plain) {
        float4* encp = (float4*)d_ws;
        enc_unsorted<<<nb * 8, 256, 0, stream>>>(coords, emb, encp, n);
        mlp_kernel<<<nb, 256, 0, stream>>>(encp,
                                           W0, b0, W1, b1, W2, b2,
                                           out, 1, n);
    } else {
        fused_kernel<<<nb, 256, 0, stream>>>(coords, emb,
                                             W0, b0, W1, b1, W2, b2, out, n);
    }
}